// Round 10
// baseline (528.781 us; speedup 1.0000x reference)
//
#include <hip/hip_runtime.h>

#define D_FEAT 64
constexpr float SLOPE = 0.01f;
constexpr float EPS_N = 1e-6f;
constexpr int SCAN_CHUNK = 2048;   // elements per scan block (256 thr x 8)
constexpr int LDT = 66;            // LDS row stride (pad 64 -> 66)
constexpr int CHUNK_E = 4096;      // edges per binning block
constexpr int BUCKET_SHIFT = 8;    // 256 nodes per bucket
constexpr int BUCKET_NODES = 256;
constexpr int NB_MAX = 512;        // max buckets supported by LDS hist
constexpr int NSPLIT = 8;          // blocks per graph for norm partial reduce

__device__ __forceinline__ float lrelu(float v) { return v >= 0.f ? v : SLOPE * v; }

// ---------------------------------------------------------------------------
// Stage 1: h = (leaky_relu(leaky_relu(x + states@Ws^T) @ W1^T)) @ W2^T
// Register-tiled f32 GEMM, 64-node tile, thread = 4 nodes x 4 ch.
// R10: 4-deep software-pipelined inner loop (load-use distance = 4 k-iters
// = 128 cyc of FMAs > ~120 cyc LDS latency) + float4 column writes for the
// inter-stage transposes (was 16 scalar stores at 8-way bank conflict).
// ---------------------------------------------------------------------------
#define FMA16(a, b)                                                           \
    acc[0][0] += a.x * b.x; acc[0][1] += a.x * b.y;                           \
    acc[0][2] += a.x * b.z; acc[0][3] += a.x * b.w;                           \
    acc[1][0] += a.y * b.x; acc[1][1] += a.y * b.y;                           \
    acc[1][2] += a.y * b.z; acc[1][3] += a.y * b.w;                           \
    acc[2][0] += a.z * b.x; acc[2][1] += a.z * b.y;                           \
    acc[2][2] += a.z * b.z; acc[2][3] += a.z * b.w;                           \
    acc[3][0] += a.w * b.x; acc[3][1] += a.w * b.y;                           \
    acc[3][2] += a.w * b.z; acc[3][3] += a.w * b.w;

#define GEMM_STAGE(SRC)                                                       \
    {                                                                         \
        float4 A0 = *(const float4*)&SRC[0 * LDT + tn4];                      \
        float4 B0 = *(const float4*)&W_t[0 * LDT + tc4];                      \
        float4 A1 = *(const float4*)&SRC[1 * LDT + tn4];                      \
        float4 B1 = *(const float4*)&W_t[1 * LDT + tc4];                      \
        float4 A2 = *(const float4*)&SRC[2 * LDT + tn4];                      \
        float4 B2 = *(const float4*)&W_t[2 * LDT + tc4];                      \
        float4 A3 = *(const float4*)&SRC[3 * LDT + tn4];                      \
        float4 B3 = *(const float4*)&W_t[3 * LDT + tc4];                      \
        _Pragma("unroll")                                                     \
        for (int k = 0; k < D_FEAT - 4; k += 4) {                             \
            FMA16(A0, B0);                                                    \
            A0 = *(const float4*)&SRC[(k + 4) * LDT + tn4];                   \
            B0 = *(const float4*)&W_t[(k + 4) * LDT + tc4];                   \
            FMA16(A1, B1);                                                    \
            A1 = *(const float4*)&SRC[(k + 5) * LDT + tn4];                   \
            B1 = *(const float4*)&W_t[(k + 5) * LDT + tc4];                   \
            FMA16(A2, B2);                                                    \
            A2 = *(const float4*)&SRC[(k + 6) * LDT + tn4];                   \
            B2 = *(const float4*)&W_t[(k + 6) * LDT + tc4];                   \
            FMA16(A3, B3);                                                    \
            A3 = *(const float4*)&SRC[(k + 7) * LDT + tn4];                   \
            B3 = *(const float4*)&W_t[(k + 7) * LDT + tc4];                   \
        }                                                                     \
        FMA16(A0, B0); FMA16(A1, B1); FMA16(A2, B2); FMA16(A3, B3);           \
    }

__global__ __launch_bounds__(256, 3) void mlp_kernel(
    const float* __restrict__ x, const float* __restrict__ states,
    const float* __restrict__ Ws, const float* __restrict__ W1,
    const float* __restrict__ W2, float* __restrict__ h, int n_nodes)
{
    __shared__ float S_t[D_FEAT * LDT];
    __shared__ float H_t[D_FEAT * LDT];
    __shared__ float W_t[D_FEAT * LDT];

    const int t   = threadIdx.x;
    const int tn  = t & 15;          // node group (4 nodes)
    const int tc  = t >> 4;          // channel group (4 ch)
    const int tn4 = tn * 4, tc4 = tc * 4;
    const int nb  = blockIdx.x * 64; // tile base node

#define STAGE_W(Wp)                                                          \
    {                                                                        \
        const int wrow = t >> 2;                                             \
        _Pragma("unroll")                                                    \
        for (int s = (t & 3); s < 16; s += 4) {                              \
            float4 wv = *reinterpret_cast<const float4*>((Wp) + wrow * 64 + s * 4); \
            W_t[(s * 4 + 0) * LDT + wrow] = wv.x;                            \
            W_t[(s * 4 + 1) * LDT + wrow] = wv.y;                            \
            W_t[(s * 4 + 2) * LDT + wrow] = wv.z;                            \
            W_t[(s * 4 + 3) * LDT + wrow] = wv.w;                            \
        }                                                                    \
    }

    STAGE_W(Ws);
    {
        const int r = t >> 4, kg = t & 15;
        #pragma unroll
        for (int i = 0; i < 4; ++i) {
            int nloc = r + i * 16;
            int node = nb + nloc;
            float4 sv = make_float4(0.f, 0.f, 0.f, 0.f);
            if (node < n_nodes)
                sv = *reinterpret_cast<const float4*>(states + (size_t)node * D_FEAT + kg * 4);
            S_t[(kg * 4 + 0) * LDT + nloc] = sv.x;
            S_t[(kg * 4 + 1) * LDT + nloc] = sv.y;
            S_t[(kg * 4 + 2) * LDT + nloc] = sv.z;
            S_t[(kg * 4 + 3) * LDT + nloc] = sv.w;
        }
    }
    __syncthreads();

    float acc[4][4];

    // ---- stage 1: h2 = lrelu(x + states @ Ws^T) ----
    #pragma unroll
    for (int i = 0; i < 4; ++i) {
        int node = nb + tn4 + i;
        if (node < n_nodes) {
            float4 xv = *reinterpret_cast<const float4*>(x + (size_t)node * D_FEAT + tc4);
            acc[i][0] = xv.x; acc[i][1] = xv.y; acc[i][2] = xv.z; acc[i][3] = xv.w;
        } else {
            acc[i][0] = acc[i][1] = acc[i][2] = acc[i][3] = 0.f;
        }
    }
    GEMM_STAGE(S_t);
    #pragma unroll
    for (int j = 0; j < 4; ++j) {
        float4 col = make_float4(lrelu(acc[0][j]), lrelu(acc[1][j]),
                                 lrelu(acc[2][j]), lrelu(acc[3][j]));
        *reinterpret_cast<float4*>(&H_t[(tc4 + j) * LDT + tn4]) = col;
    }
    __syncthreads();

    STAGE_W(W1);
    __syncthreads();

    // ---- stage 2: h3 = lrelu(h2 @ W1^T) ----
    #pragma unroll
    for (int i = 0; i < 4; ++i)
        #pragma unroll
        for (int j = 0; j < 4; ++j)
            acc[i][j] = 0.f;
    GEMM_STAGE(H_t);
    #pragma unroll
    for (int j = 0; j < 4; ++j) {
        float4 col = make_float4(lrelu(acc[0][j]), lrelu(acc[1][j]),
                                 lrelu(acc[2][j]), lrelu(acc[3][j]));
        *reinterpret_cast<float4*>(&S_t[(tc4 + j) * LDT + tn4]) = col;  // h3 overwrites S_t
    }
    __syncthreads();

    STAGE_W(W2);
    __syncthreads();

    // ---- stage 3: h = h3 @ W2^T ----
    #pragma unroll
    for (int i = 0; i < 4; ++i)
        #pragma unroll
        for (int j = 0; j < 4; ++j)
            acc[i][j] = 0.f;
    GEMM_STAGE(S_t);
    #pragma unroll
    for (int i = 0; i < 4; ++i) {
        int node = nb + tn4 + i;
        if (node < n_nodes) {
            float4 o = make_float4(acc[i][0], acc[i][1], acc[i][2], acc[i][3]);
            *reinterpret_cast<float4*>(h + (size_t)node * D_FEAT + tc4) = o;
        }
    }
#undef STAGE_W
}

// ---------------------------------------------------------------------------
// Pass A: per-chunk bucket histogram (bucket = dst >> BUCKET_SHIFT).
// ---------------------------------------------------------------------------
__global__ __launch_bounds__(256) void binhist_kernel(
    const int* __restrict__ eidx, int* __restrict__ bh,
    int n_edges, int nb, int nch)
{
    __shared__ int hist[NB_MAX];
    const int c = blockIdx.x, t = threadIdx.x;
    for (int i = t; i < nb; i += 256) hist[i] = 0;
    __syncthreads();
    const int base = c * CHUNK_E;
    #pragma unroll 4
    for (int k = 0; k < CHUNK_E / 256; ++k) {
        int e = base + k * 256 + t;
        if (e < n_edges) atomicAdd(&hist[eidx[e] >> BUCKET_SHIFT], 1);
    }
    __syncthreads();
    for (int i = t; i < nb; i += 256) bh[i * nch + c] = hist[i];
}

// ---------------------------------------------------------------------------
// Scan: local exclusive per 2048-chunk (scan1) + partials scan (scan2).
// Consumers add partials[idx/SCAN_CHUNK] inline (no scan3 pass).
// ---------------------------------------------------------------------------
__global__ __launch_bounds__(256) void scan1_kernel(
    const int* __restrict__ in, int* __restrict__ out,
    int* __restrict__ partials, int n)
{
    __shared__ int s[256];
    const int b = blockIdx.x, t = threadIdx.x;
    const int base = b * SCAN_CHUNK + t * 8;
    int v[8]; int sum = 0;
    #pragma unroll
    for (int i = 0; i < 8; ++i) {
        v[i] = (base + i < n) ? in[base + i] : 0;
        sum += v[i];
    }
    s[t] = sum;
    __syncthreads();
    for (int off = 1; off < 256; off <<= 1) {
        int y = (t >= off) ? s[t - off] : 0;
        __syncthreads();
        s[t] += y;
        __syncthreads();
    }
    int excl = s[t] - sum;
    #pragma unroll
    for (int i = 0; i < 8; ++i) {
        if (base + i < n) out[base + i] = excl;
        excl += v[i];
    }
    if (t == 255) partials[b] = s[255];
}

__global__ __launch_bounds__(256) void scan2_kernel(int* partials, int nchunks)
{
    __shared__ int s[256];
    const int t = threadIdx.x;
    int v = (t < nchunks) ? partials[t] : 0;
    s[t] = v;
    __syncthreads();
    for (int off = 1; off < 256; off <<= 1) {
        int y = (t >= off) ? s[t - off] : 0;
        __syncthreads();
        s[t] += y;
        __syncthreads();
    }
    if (t < nchunks) partials[t] = s[t] - v;      // exclusive
}

// ---------------------------------------------------------------------------
// Pass B: binned scatter into per-(bucket,chunk) contiguous runs.
// rec.x = (dstLocal << 20) | src,  rec.y = w bits.
// Global offset = bh[idx] + partials[idx / SCAN_CHUNK] (scan3 folded in).
// ---------------------------------------------------------------------------
__global__ __launch_bounds__(256) void binscatter_kernel(
    const int* __restrict__ eidx, const float* __restrict__ w,
    const int* __restrict__ bh, const int* __restrict__ partials,
    int2* __restrict__ rec, int n_edges, int nb, int nch)
{
    __shared__ int cur[NB_MAX];
    const int c = blockIdx.x, t = threadIdx.x;
    for (int i = t; i < nb; i += 256) {
        int idx = i * nch + c;
        cur[i] = bh[idx] + partials[idx / SCAN_CHUNK];
    }
    __syncthreads();
    const int base = c * CHUNK_E;
    #pragma unroll 4
    for (int k = 0; k < CHUNK_E / 256; ++k) {
        int e = base + k * 256 + t;
        if (e < n_edges) {
            int dst = eidx[e];
            int src = eidx[n_edges + e];
            float wv = w[e];
            int b = dst >> BUCKET_SHIFT;
            int dl = dst & (BUCKET_NODES - 1);
            int pos = atomicAdd(&cur[b], 1);
            rec[pos] = make_int2((dl << 20) | src, __float_as_int(wv));
        }
    }
}

// ---------------------------------------------------------------------------
// Pass B2: per-bucket counting sort into per-NODE order + row_start build.
// ---------------------------------------------------------------------------
__global__ __launch_bounds__(256) void bucket_sort_kernel(
    const int* __restrict__ bh, const int* __restrict__ partials,
    const int2* __restrict__ rec, int2* __restrict__ rec2,
    int* __restrict__ row_start, int n_edges, int nb, int nch, int n_nodes)
{
    __shared__ int cnt[BUCKET_NODES];
    __shared__ int s[BUCKET_NODES];
    __shared__ int pos[BUCKET_NODES];

    const int b = blockIdx.x, t = threadIdx.x;
    const int iS = b * nch;
    const int S = bh[iS] + partials[iS / SCAN_CHUNK];
    int E = n_edges;
    if (b + 1 < nb) {
        int iE = (b + 1) * nch;
        E = bh[iE] + partials[iE / SCAN_CHUNK];
    }

    cnt[t] = 0;
    __syncthreads();
    for (int i = S + t; i < E; i += 256)
        atomicAdd(&cnt[rec[i].x >> 20], 1);
    __syncthreads();

    // exclusive scan of cnt
    int my = cnt[t];
    s[t] = my;
    __syncthreads();
    for (int off = 1; off < 256; off <<= 1) {
        int y = (t >= off) ? s[t - off] : 0;
        __syncthreads();
        s[t] += y;
        __syncthreads();
    }
    int excl = s[t] - my;
    pos[t] = S + excl;
    const int node = (b << BUCKET_SHIFT) + t;
    if (node < n_nodes) row_start[node] = S + excl;
    if (b == nb - 1 && t == 0) row_start[n_nodes] = n_edges;
    __syncthreads();

    for (int i = S + t; i < E; i += 256) {
        int2 r = rec[i];
        int p = atomicAdd(&pos[r.x >> 20], 1);
        rec2[p] = r;
    }
}

// ---------------------------------------------------------------------------
// Pass C: atomic-free gather. One wave per destination node, lane = channel.
// ---------------------------------------------------------------------------
__global__ __launch_bounds__(256, 8) void node_gather_kernel(
    const int* __restrict__ row_start, const int2* __restrict__ rec2,
    const float* __restrict__ h, float* __restrict__ agg, int n_nodes)
{
    const int node = blockIdx.x * 4 + (threadIdx.x >> 6);
    const int lane = threadIdx.x & 63;
    if (node >= n_nodes) return;

    const int start = row_start[node];
    const int end   = row_start[node + 1];

    float a0 = 0.f, a1 = 0.f, a2 = 0.f, a3 = 0.f;
    int i = start;
    for (; i + 4 <= end; i += 4) {
        int2 r0 = rec2[i];
        int2 r1 = rec2[i + 1];
        int2 r2 = rec2[i + 2];
        int2 r3 = rec2[i + 3];
        float h0 = h[(size_t)(r0.x & 0xFFFFF) * D_FEAT + lane];
        float h1 = h[(size_t)(r1.x & 0xFFFFF) * D_FEAT + lane];
        float h2 = h[(size_t)(r2.x & 0xFFFFF) * D_FEAT + lane];
        float h3 = h[(size_t)(r3.x & 0xFFFFF) * D_FEAT + lane];
        a0 += __int_as_float(r0.y) * h0;
        a1 += __int_as_float(r1.y) * h1;
        a2 += __int_as_float(r2.y) * h2;
        a3 += __int_as_float(r3.y) * h3;
    }
    for (; i < end; ++i) {
        int2 r = rec2[i];
        a0 += __int_as_float(r.y) * h[(size_t)(r.x & 0xFFFFF) * D_FEAT + lane];
    }
    agg[(size_t)node * D_FEAT + lane] = (a0 + a1) + (a2 + a3);
}

// ---------------------------------------------------------------------------
// Fallback scatter (atomics) if workspace too small / shape unsupported
// ---------------------------------------------------------------------------
__global__ __launch_bounds__(256) void scatter_atomic_kernel(
    const int* __restrict__ eidx, const float* __restrict__ w,
    const float* __restrict__ h, float* __restrict__ agg, int n_edges)
{
    long long t = (long long)blockIdx.x * blockDim.x + threadIdx.x;
    int e = (int)(t >> 4);
    if (e >= n_edges) return;
    int c = ((int)t & 15) * 4;
    int dst = eidx[e];
    int src = eidx[n_edges + e];
    float wv = w[e];
    const float4 hv = *reinterpret_cast<const float4*>(h + (size_t)src * D_FEAT + c);
    float* p = agg + (size_t)dst * D_FEAT + c;
    unsafeAtomicAdd(p + 0, wv * hv.x);
    unsafeAtomicAdd(p + 1, wv * hv.y);
    unsafeAtomicAdd(p + 2, wv * hv.z);
    unsafeAtomicAdd(p + 3, wv * hv.w);
}

// ---------------------------------------------------------------------------
// GraphNorm, parallelized: partial reduce -> finalize -> apply.
// ---------------------------------------------------------------------------
__global__ __launch_bounds__(256) void norm_part_kernel(
    const float* __restrict__ io, float* __restrict__ part, int npg)
{
    const int g = blockIdx.x / NSPLIT;
    const int s = blockIdx.x % NSPLIT;
    const int t = threadIdx.x;
    const int j = t & 63;
    const int r = t >> 6;
    const int chunk = (npg + NSPLIT - 1) / NSPLIT;
    const int n0 = s * chunk;
    const int n1 = min(npg, n0 + chunk);
    const size_t base = (size_t)g * npg * D_FEAT;

    float sum = 0.f, sq = 0.f;
    for (int n = n0 + r; n < n1; n += 4) {
        float v = io[base + (size_t)n * D_FEAT + j];
        sum += v; sq += v * v;
    }
    __shared__ float s_red[2][4][64];
    s_red[0][r][j] = sum;
    s_red[1][r][j] = sq;
    __syncthreads();
    if (r == 0) {
        float S = s_red[0][0][j] + s_red[0][1][j] + s_red[0][2][j] + s_red[0][3][j];
        float Q = s_red[1][0][j] + s_red[1][1][j] + s_red[1][2][j] + s_red[1][3][j];
        part[(size_t)blockIdx.x * 128 + j]      = S;
        part[(size_t)blockIdx.x * 128 + 64 + j] = Q;
    }
}

__global__ __launch_bounds__(64) void norm_fin_kernel(
    const float* __restrict__ part, float* __restrict__ musc,
    const float* __restrict__ gamma, int npg)
{
    const int g = blockIdx.x;
    const int j = threadIdx.x;
    float S = 0.f, Q = 0.f;
    #pragma unroll
    for (int s = 0; s < NSPLIT; ++s) {
        S += part[(size_t)(g * NSPLIT + s) * 128 + j];
        Q += part[(size_t)(g * NSPLIT + s) * 128 + 64 + j];
    }
    float cnt = (float)npg;
    float mu = S / cnt;
    float var = (Q - cnt * mu * mu) / fmaxf(cnt - 1.f, 1.f);
    var = fmaxf(var, 0.f);
    musc[g * 128 + j]      = mu;
    musc[g * 128 + 64 + j] = gamma[j] / (sqrtf(var) + EPS_N);
}

__global__ __launch_bounds__(256) void norm_apply_kernel(
    float* __restrict__ io, const float* __restrict__ musc,
    const float* __restrict__ beta, int n_nodes, int npg)
{
    const int nf4 = n_nodes * 16;   // float4 count
    for (int i4 = blockIdx.x * blockDim.x + threadIdx.x; i4 < nf4;
         i4 += gridDim.x * blockDim.x) {
        int node = i4 >> 4;
        int j0 = (i4 & 15) * 4;
        int g = node / npg;
        float4 v  = *reinterpret_cast<float4*>(io + (size_t)i4 * 4);
        float4 mu = *reinterpret_cast<const float4*>(musc + g * 128 + j0);
        float4 sc = *reinterpret_cast<const float4*>(musc + g * 128 + 64 + j0);
        float4 be = *reinterpret_cast<const float4*>(beta + j0);
        v.x = (v.x - mu.x) * sc.x + be.x;
        v.y = (v.y - mu.y) * sc.y + be.y;
        v.z = (v.z - mu.z) * sc.z + be.z;
        v.w = (v.w - mu.w) * sc.w + be.w;
        *reinterpret_cast<float4*>(io + (size_t)i4 * 4) = v;
    }
}

extern "C" void kernel_launch(void* const* d_in, const int* in_sizes, int n_in,
                              void* d_out, int out_size, void* d_ws, size_t ws_size,
                              hipStream_t stream)
{
    const float* x      = (const float*)d_in[0];
    const float* states = (const float*)d_in[1];
    const int*   eidx   = (const int*)d_in[2];
    const float* w      = (const float*)d_in[3];
    const float* Ws     = (const float*)d_in[6];
    const float* W1     = (const float*)d_in[7];
    const float* W2     = (const float*)d_in[8];
    const float* gamma  = (const float*)d_in[9];
    const float* beta   = (const float*)d_in[10];

    const int n_nodes  = in_sizes[0] / D_FEAT;
    const int n_edges  = in_sizes[3];
    const int n_graphs = in_sizes[5];
    const int npg      = n_nodes / n_graphs;

    const int nb  = (n_nodes + BUCKET_NODES - 1) / BUCKET_NODES;  // 391
    const int nch = (n_edges + CHUNK_E - 1) / CHUNK_E;            // 293
    const int nscan = nb * nch;

    // workspace layout: h | rec | rec2 | bh | partials | row_start
    char* ws = (char*)d_ws;
    size_t hBytes    = (size_t)n_nodes * D_FEAT * sizeof(float);  // 25.6 MB
    size_t recBytes  = (size_t)n_edges * sizeof(int2);            // 9.6 MB
    size_t bhBytes   = (size_t)nscan * sizeof(int);               // 458 KB
    size_t partBytes = 256 * sizeof(int);
    size_t rsBytes   = (size_t)(n_nodes + 1) * sizeof(int);
    size_t need = hBytes + 2 * recBytes + bhBytes + partBytes + rsBytes;

    float* h   = (float*)ws;
    float* agg = (float*)d_out;

    // norm scratch aliases the rec region (rec is dead before norm runs)
    float* nrm_part = (float*)(ws + hBytes);
    float* nrm_musc = nrm_part + (size_t)n_graphs * NSPLIT * 128;

    mlp_kernel<<<(n_nodes + 63) / 64, 256, 0, stream>>>(x, states, Ws, W1, W2, h, n_nodes);

    const bool ok = (ws_size >= need) && (nb <= NB_MAX) && (n_nodes < (1 << 20));
    if (ok) {
        int2* rec      = (int2*)(ws + hBytes);
        int2* rec2     = (int2*)(ws + hBytes + recBytes);
        int*  bh       = (int*)(ws + hBytes + 2 * recBytes);
        int*  partials = (int*)(ws + hBytes + 2 * recBytes + bhBytes);
        int*  row_start= (int*)(ws + hBytes + 2 * recBytes + bhBytes + partBytes);

        binhist_kernel<<<nch, 256, 0, stream>>>(eidx, bh, n_edges, nb, nch);

        int nchunks = (nscan + SCAN_CHUNK - 1) / SCAN_CHUNK;
        scan1_kernel<<<nchunks, 256, 0, stream>>>(bh, bh, partials, nscan);  // in-place
        scan2_kernel<<<1, 256, 0, stream>>>(partials, nchunks);

        binscatter_kernel<<<nch, 256, 0, stream>>>(eidx, w, bh, partials, rec,
                                                   n_edges, nb, nch);

        bucket_sort_kernel<<<nb, 256, 0, stream>>>(bh, partials, rec, rec2, row_start,
                                                   n_edges, nb, nch, n_nodes);

        node_gather_kernel<<<(n_nodes + 3) / 4, 256, 0, stream>>>(row_start, rec2, h,
                                                                  agg, n_nodes);
    } else {
        hipMemsetAsync(agg, 0, hBytes, stream);
        long long sthreads = (long long)n_edges * 16;
        int sblocks = (int)((sthreads + 255) / 256);
        scatter_atomic_kernel<<<sblocks, 256, 0, stream>>>(eidx, w, h, agg, n_edges);
    }

    norm_part_kernel<<<n_graphs * NSPLIT, 256, 0, stream>>>(agg, nrm_part, npg);
    norm_fin_kernel<<<n_graphs, 64, 0, stream>>>(nrm_part, nrm_musc, gamma, npg);
    norm_apply_kernel<<<1024, 256, 0, stream>>>(agg, nrm_musc, beta, n_nodes, npg);
}

// Round 11
// 174.996 us; speedup vs baseline: 3.0217x; 3.0217x over previous
//
#include <hip/hip_runtime.h>

#define D_FEAT 64
constexpr float SLOPE = 0.01f;
constexpr float EPS_N = 1e-6f;
constexpr int SCAN_CHUNK = 2048;   // elements per scan block (256 thr x 8)
constexpr int LDT = 66;            // LDS row stride (pad 64 -> 66)
constexpr int CHUNK_E = 4096;      // edges per binning block
constexpr int BUCKET_SHIFT = 8;    // 256 nodes per bucket
constexpr int BUCKET_NODES = 256;
constexpr int NB_MAX = 512;        // max buckets supported by LDS hist
constexpr int NSPLIT = 8;          // blocks per graph for norm partial reduce

__device__ __forceinline__ float lrelu(float v) { return v >= 0.f ? v : SLOPE * v; }

// ---------------------------------------------------------------------------
// Stage 1: h = (leaky_relu(leaky_relu(x + states@Ws^T) @ W1^T)) @ W2^T
// Register-tiled f32 GEMM, 64-node tile, thread = 4 nodes x 4 ch.
// R11: R9's inner loop (unroll 8, av/bv — 68 VGPR, no spill; R10's 4-deep
// pipeline spilled to scratch: 1.3 GB HBM/dispatch) + float4 COLUMN writes
// for the inter-stage transposes (scalar version was 8-way bank conflict;
// float4 tiles all 32 banks at the b128 minimum -> conflict-free).
// ---------------------------------------------------------------------------
__global__ __launch_bounds__(256, 3) void mlp_kernel(
    const float* __restrict__ x, const float* __restrict__ states,
    const float* __restrict__ Ws, const float* __restrict__ W1,
    const float* __restrict__ W2, float* __restrict__ h, int n_nodes)
{
    __shared__ float S_t[D_FEAT * LDT];
    __shared__ float H_t[D_FEAT * LDT];
    __shared__ float W_t[D_FEAT * LDT];

    const int t   = threadIdx.x;
    const int tn  = t & 15;          // node group (4 nodes)
    const int tc  = t >> 4;          // channel group (4 ch)
    const int tn4 = tn * 4, tc4 = tc * 4;
    const int nb  = blockIdx.x * 64; // tile base node

#define STAGE_W(Wp)                                                          \
    {                                                                        \
        const int wrow = t >> 2;                                             \
        _Pragma("unroll")                                                    \
        for (int s = (t & 3); s < 16; s += 4) {                              \
            float4 wv = *reinterpret_cast<const float4*>((Wp) + wrow * 64 + s * 4); \
            W_t[(s * 4 + 0) * LDT + wrow] = wv.x;                            \
            W_t[(s * 4 + 1) * LDT + wrow] = wv.y;                            \
            W_t[(s * 4 + 2) * LDT + wrow] = wv.z;                            \
            W_t[(s * 4 + 3) * LDT + wrow] = wv.w;                            \
        }                                                                    \
    }

#define GEMM_LOOP(SRC)                                                       \
    _Pragma("unroll 8")                                                      \
    for (int k = 0; k < D_FEAT; ++k) {                                       \
        float4 a = *reinterpret_cast<const float4*>(&SRC[k * LDT + tn4]);    \
        float4 b = *reinterpret_cast<const float4*>(&W_t[k * LDT + tc4]);    \
        const float av[4] = {a.x, a.y, a.z, a.w};                            \
        const float bv[4] = {b.x, b.y, b.z, b.w};                            \
        _Pragma("unroll")                                                    \
        for (int i = 0; i < 4; ++i)                                          \
            _Pragma("unroll")                                                \
            for (int j = 0; j < 4; ++j)                                      \
                acc[i][j] += av[i] * bv[j];                                  \
    }

    STAGE_W(Ws);
    {
        const int r = t >> 4, kg = t & 15;
        #pragma unroll
        for (int i = 0; i < 4; ++i) {
            int nloc = r + i * 16;
            int node = nb + nloc;
            float4 sv = make_float4(0.f, 0.f, 0.f, 0.f);
            if (node < n_nodes)
                sv = *reinterpret_cast<const float4*>(states + (size_t)node * D_FEAT + kg * 4);
            S_t[(kg * 4 + 0) * LDT + nloc] = sv.x;
            S_t[(kg * 4 + 1) * LDT + nloc] = sv.y;
            S_t[(kg * 4 + 2) * LDT + nloc] = sv.z;
            S_t[(kg * 4 + 3) * LDT + nloc] = sv.w;
        }
    }
    __syncthreads();

    float acc[4][4];

    // ---- stage 1: h2 = lrelu(x + states @ Ws^T) ----
    #pragma unroll
    for (int i = 0; i < 4; ++i) {
        int node = nb + tn4 + i;
        if (node < n_nodes) {
            float4 xv = *reinterpret_cast<const float4*>(x + (size_t)node * D_FEAT + tc4);
            acc[i][0] = xv.x; acc[i][1] = xv.y; acc[i][2] = xv.z; acc[i][3] = xv.w;
        } else {
            acc[i][0] = acc[i][1] = acc[i][2] = acc[i][3] = 0.f;
        }
    }
    GEMM_LOOP(S_t);
    #pragma unroll
    for (int j = 0; j < 4; ++j) {
        float4 col = make_float4(lrelu(acc[0][j]), lrelu(acc[1][j]),
                                 lrelu(acc[2][j]), lrelu(acc[3][j]));
        *reinterpret_cast<float4*>(&H_t[(tc4 + j) * LDT + tn4]) = col;
    }
    __syncthreads();

    STAGE_W(W1);
    __syncthreads();

    // ---- stage 2: h3 = lrelu(h2 @ W1^T) ----
    #pragma unroll
    for (int i = 0; i < 4; ++i)
        #pragma unroll
        for (int j = 0; j < 4; ++j)
            acc[i][j] = 0.f;
    GEMM_LOOP(H_t);
    #pragma unroll
    for (int j = 0; j < 4; ++j) {
        float4 col = make_float4(lrelu(acc[0][j]), lrelu(acc[1][j]),
                                 lrelu(acc[2][j]), lrelu(acc[3][j]));
        *reinterpret_cast<float4*>(&S_t[(tc4 + j) * LDT + tn4]) = col;  // h3 overwrites S_t
    }
    __syncthreads();

    STAGE_W(W2);
    __syncthreads();

    // ---- stage 3: h = h3 @ W2^T ----
    #pragma unroll
    for (int i = 0; i < 4; ++i)
        #pragma unroll
        for (int j = 0; j < 4; ++j)
            acc[i][j] = 0.f;
    GEMM_LOOP(S_t);
    #pragma unroll
    for (int i = 0; i < 4; ++i) {
        int node = nb + tn4 + i;
        if (node < n_nodes) {
            float4 o = make_float4(acc[i][0], acc[i][1], acc[i][2], acc[i][3]);
            *reinterpret_cast<float4*>(h + (size_t)node * D_FEAT + tc4) = o;
        }
    }
#undef STAGE_W
#undef GEMM_LOOP
}

// ---------------------------------------------------------------------------
// Pass A: per-chunk bucket histogram (bucket = dst >> BUCKET_SHIFT).
// ---------------------------------------------------------------------------
__global__ __launch_bounds__(256) void binhist_kernel(
    const int* __restrict__ eidx, int* __restrict__ bh,
    int n_edges, int nb, int nch)
{
    __shared__ int hist[NB_MAX];
    const int c = blockIdx.x, t = threadIdx.x;
    for (int i = t; i < nb; i += 256) hist[i] = 0;
    __syncthreads();
    const int base = c * CHUNK_E;
    #pragma unroll 4
    for (int k = 0; k < CHUNK_E / 256; ++k) {
        int e = base + k * 256 + t;
        if (e < n_edges) atomicAdd(&hist[eidx[e] >> BUCKET_SHIFT], 1);
    }
    __syncthreads();
    for (int i = t; i < nb; i += 256) bh[i * nch + c] = hist[i];
}

// ---------------------------------------------------------------------------
// Scan: local exclusive per 2048-chunk (scan1) + partials scan (scan2).
// Consumers add partials[idx/SCAN_CHUNK] inline (no scan3 pass).
// ---------------------------------------------------------------------------
__global__ __launch_bounds__(256) void scan1_kernel(
    const int* __restrict__ in, int* __restrict__ out,
    int* __restrict__ partials, int n)
{
    __shared__ int s[256];
    const int b = blockIdx.x, t = threadIdx.x;
    const int base = b * SCAN_CHUNK + t * 8;
    int v[8]; int sum = 0;
    #pragma unroll
    for (int i = 0; i < 8; ++i) {
        v[i] = (base + i < n) ? in[base + i] : 0;
        sum += v[i];
    }
    s[t] = sum;
    __syncthreads();
    for (int off = 1; off < 256; off <<= 1) {
        int y = (t >= off) ? s[t - off] : 0;
        __syncthreads();
        s[t] += y;
        __syncthreads();
    }
    int excl = s[t] - sum;
    #pragma unroll
    for (int i = 0; i < 8; ++i) {
        if (base + i < n) out[base + i] = excl;
        excl += v[i];
    }
    if (t == 255) partials[b] = s[255];
}

__global__ __launch_bounds__(256) void scan2_kernel(int* partials, int nchunks)
{
    __shared__ int s[256];
    const int t = threadIdx.x;
    int v = (t < nchunks) ? partials[t] : 0;
    s[t] = v;
    __syncthreads();
    for (int off = 1; off < 256; off <<= 1) {
        int y = (t >= off) ? s[t - off] : 0;
        __syncthreads();
        s[t] += y;
        __syncthreads();
    }
    if (t < nchunks) partials[t] = s[t] - v;      // exclusive
}

// ---------------------------------------------------------------------------
// Pass B: binned scatter into per-(bucket,chunk) contiguous runs.
// rec.x = (dstLocal << 20) | src,  rec.y = w bits.
// Global offset = bh[idx] + partials[idx / SCAN_CHUNK] (scan3 folded in).
// ---------------------------------------------------------------------------
__global__ __launch_bounds__(256) void binscatter_kernel(
    const int* __restrict__ eidx, const float* __restrict__ w,
    const int* __restrict__ bh, const int* __restrict__ partials,
    int2* __restrict__ rec, int n_edges, int nb, int nch)
{
    __shared__ int cur[NB_MAX];
    const int c = blockIdx.x, t = threadIdx.x;
    for (int i = t; i < nb; i += 256) {
        int idx = i * nch + c;
        cur[i] = bh[idx] + partials[idx / SCAN_CHUNK];
    }
    __syncthreads();
    const int base = c * CHUNK_E;
    #pragma unroll 4
    for (int k = 0; k < CHUNK_E / 256; ++k) {
        int e = base + k * 256 + t;
        if (e < n_edges) {
            int dst = eidx[e];
            int src = eidx[n_edges + e];
            float wv = w[e];
            int b = dst >> BUCKET_SHIFT;
            int dl = dst & (BUCKET_NODES - 1);
            int pos = atomicAdd(&cur[b], 1);
            rec[pos] = make_int2((dl << 20) | src, __float_as_int(wv));
        }
    }
}

// ---------------------------------------------------------------------------
// Pass B2: per-bucket counting sort into per-NODE order + row_start build.
// ---------------------------------------------------------------------------
__global__ __launch_bounds__(256) void bucket_sort_kernel(
    const int* __restrict__ bh, const int* __restrict__ partials,
    const int2* __restrict__ rec, int2* __restrict__ rec2,
    int* __restrict__ row_start, int n_edges, int nb, int nch, int n_nodes)
{
    __shared__ int cnt[BUCKET_NODES];
    __shared__ int s[BUCKET_NODES];
    __shared__ int pos[BUCKET_NODES];

    const int b = blockIdx.x, t = threadIdx.x;
    const int iS = b * nch;
    const int S = bh[iS] + partials[iS / SCAN_CHUNK];
    int E = n_edges;
    if (b + 1 < nb) {
        int iE = (b + 1) * nch;
        E = bh[iE] + partials[iE / SCAN_CHUNK];
    }

    cnt[t] = 0;
    __syncthreads();
    for (int i = S + t; i < E; i += 256)
        atomicAdd(&cnt[rec[i].x >> 20], 1);
    __syncthreads();

    // exclusive scan of cnt
    int my = cnt[t];
    s[t] = my;
    __syncthreads();
    for (int off = 1; off < 256; off <<= 1) {
        int y = (t >= off) ? s[t - off] : 0;
        __syncthreads();
        s[t] += y;
        __syncthreads();
    }
    int excl = s[t] - my;
    pos[t] = S + excl;
    const int node = (b << BUCKET_SHIFT) + t;
    if (node < n_nodes) row_start[node] = S + excl;
    if (b == nb - 1 && t == 0) row_start[n_nodes] = n_edges;
    __syncthreads();

    for (int i = S + t; i < E; i += 256) {
        int2 r = rec[i];
        int p = atomicAdd(&pos[r.x >> 20], 1);
        rec2[p] = r;
    }
}

// ---------------------------------------------------------------------------
// Pass C: atomic-free gather. One wave per destination node, lane = channel.
// ---------------------------------------------------------------------------
__global__ __launch_bounds__(256, 8) void node_gather_kernel(
    const int* __restrict__ row_start, const int2* __restrict__ rec2,
    const float* __restrict__ h, float* __restrict__ agg, int n_nodes)
{
    const int node = blockIdx.x * 4 + (threadIdx.x >> 6);
    const int lane = threadIdx.x & 63;
    if (node >= n_nodes) return;

    const int start = row_start[node];
    const int end   = row_start[node + 1];

    float a0 = 0.f, a1 = 0.f, a2 = 0.f, a3 = 0.f;
    int i = start;
    for (; i + 4 <= end; i += 4) {
        int2 r0 = rec2[i];
        int2 r1 = rec2[i + 1];
        int2 r2 = rec2[i + 2];
        int2 r3 = rec2[i + 3];
        float h0 = h[(size_t)(r0.x & 0xFFFFF) * D_FEAT + lane];
        float h1 = h[(size_t)(r1.x & 0xFFFFF) * D_FEAT + lane];
        float h2 = h[(size_t)(r2.x & 0xFFFFF) * D_FEAT + lane];
        float h3 = h[(size_t)(r3.x & 0xFFFFF) * D_FEAT + lane];
        a0 += __int_as_float(r0.y) * h0;
        a1 += __int_as_float(r1.y) * h1;
        a2 += __int_as_float(r2.y) * h2;
        a3 += __int_as_float(r3.y) * h3;
    }
    for (; i < end; ++i) {
        int2 r = rec2[i];
        a0 += __int_as_float(r.y) * h[(size_t)(r.x & 0xFFFFF) * D_FEAT + lane];
    }
    agg[(size_t)node * D_FEAT + lane] = (a0 + a1) + (a2 + a3);
}

// ---------------------------------------------------------------------------
// Fallback scatter (atomics) if workspace too small / shape unsupported
// ---------------------------------------------------------------------------
__global__ __launch_bounds__(256) void scatter_atomic_kernel(
    const int* __restrict__ eidx, const float* __restrict__ w,
    const float* __restrict__ h, float* __restrict__ agg, int n_edges)
{
    long long t = (long long)blockIdx.x * blockDim.x + threadIdx.x;
    int e = (int)(t >> 4);
    if (e >= n_edges) return;
    int c = ((int)t & 15) * 4;
    int dst = eidx[e];
    int src = eidx[n_edges + e];
    float wv = w[e];
    const float4 hv = *reinterpret_cast<const float4*>(h + (size_t)src * D_FEAT + c);
    float* p = agg + (size_t)dst * D_FEAT + c;
    unsafeAtomicAdd(p + 0, wv * hv.x);
    unsafeAtomicAdd(p + 1, wv * hv.y);
    unsafeAtomicAdd(p + 2, wv * hv.z);
    unsafeAtomicAdd(p + 3, wv * hv.w);
}

// ---------------------------------------------------------------------------
// GraphNorm, parallelized: partial reduce -> finalize -> apply.
// ---------------------------------------------------------------------------
__global__ __launch_bounds__(256) void norm_part_kernel(
    const float* __restrict__ io, float* __restrict__ part, int npg)
{
    const int g = blockIdx.x / NSPLIT;
    const int s = blockIdx.x % NSPLIT;
    const int t = threadIdx.x;
    const int j = t & 63;
    const int r = t >> 6;
    const int chunk = (npg + NSPLIT - 1) / NSPLIT;
    const int n0 = s * chunk;
    const int n1 = min(npg, n0 + chunk);
    const size_t base = (size_t)g * npg * D_FEAT;

    float sum = 0.f, sq = 0.f;
    for (int n = n0 + r; n < n1; n += 4) {
        float v = io[base + (size_t)n * D_FEAT + j];
        sum += v; sq += v * v;
    }
    __shared__ float s_red[2][4][64];
    s_red[0][r][j] = sum;
    s_red[1][r][j] = sq;
    __syncthreads();
    if (r == 0) {
        float S = s_red[0][0][j] + s_red[0][1][j] + s_red[0][2][j] + s_red[0][3][j];
        float Q = s_red[1][0][j] + s_red[1][1][j] + s_red[1][2][j] + s_red[1][3][j];
        part[(size_t)blockIdx.x * 128 + j]      = S;
        part[(size_t)blockIdx.x * 128 + 64 + j] = Q;
    }
}

__global__ __launch_bounds__(64) void norm_fin_kernel(
    const float* __restrict__ part, float* __restrict__ musc,
    const float* __restrict__ gamma, int npg)
{
    const int g = blockIdx.x;
    const int j = threadIdx.x;
    float S = 0.f, Q = 0.f;
    #pragma unroll
    for (int s = 0; s < NSPLIT; ++s) {
        S += part[(size_t)(g * NSPLIT + s) * 128 + j];
        Q += part[(size_t)(g * NSPLIT + s) * 128 + 64 + j];
    }
    float cnt = (float)npg;
    float mu = S / cnt;
    float var = (Q - cnt * mu * mu) / fmaxf(cnt - 1.f, 1.f);
    var = fmaxf(var, 0.f);
    musc[g * 128 + j]      = mu;
    musc[g * 128 + 64 + j] = gamma[j] / (sqrtf(var) + EPS_N);
}

__global__ __launch_bounds__(256) void norm_apply_kernel(
    float* __restrict__ io, const float* __restrict__ musc,
    const float* __restrict__ beta, int n_nodes, int npg)
{
    const int nf4 = n_nodes * 16;   // float4 count
    for (int i4 = blockIdx.x * blockDim.x + threadIdx.x; i4 < nf4;
         i4 += gridDim.x * blockDim.x) {
        int node = i4 >> 4;
        int j0 = (i4 & 15) * 4;
        int g = node / npg;
        float4 v  = *reinterpret_cast<float4*>(io + (size_t)i4 * 4);
        float4 mu = *reinterpret_cast<const float4*>(musc + g * 128 + j0);
        float4 sc = *reinterpret_cast<const float4*>(musc + g * 128 + 64 + j0);
        float4 be = *reinterpret_cast<const float4*>(beta + j0);
        v.x = (v.x - mu.x) * sc.x + be.x;
        v.y = (v.y - mu.y) * sc.y + be.y;
        v.z = (v.z - mu.z) * sc.z + be.z;
        v.w = (v.w - mu.w) * sc.w + be.w;
        *reinterpret_cast<float4*>(io + (size_t)i4 * 4) = v;
    }
}

extern "C" void kernel_launch(void* const* d_in, const int* in_sizes, int n_in,
                              void* d_out, int out_size, void* d_ws, size_t ws_size,
                              hipStream_t stream)
{
    const float* x      = (const float*)d_in[0];
    const float* states = (const float*)d_in[1];
    const int*   eidx   = (const int*)d_in[2];
    const float* w      = (const float*)d_in[3];
    const float* Ws     = (const float*)d_in[6];
    const float* W1     = (const float*)d_in[7];
    const float* W2     = (const float*)d_in[8];
    const float* gamma  = (const float*)d_in[9];
    const float* beta   = (const float*)d_in[10];

    const int n_nodes  = in_sizes[0] / D_FEAT;
    const int n_edges  = in_sizes[3];
    const int n_graphs = in_sizes[5];
    const int npg      = n_nodes / n_graphs;

    const int nb  = (n_nodes + BUCKET_NODES - 1) / BUCKET_NODES;  // 391
    const int nch = (n_edges + CHUNK_E - 1) / CHUNK_E;            // 293
    const int nscan = nb * nch;

    // workspace layout: h | rec | rec2 | bh | partials | row_start
    char* ws = (char*)d_ws;
    size_t hBytes    = (size_t)n_nodes * D_FEAT * sizeof(float);  // 25.6 MB
    size_t recBytes  = (size_t)n_edges * sizeof(int2);            // 9.6 MB
    size_t bhBytes   = (size_t)nscan * sizeof(int);               // 458 KB
    size_t partBytes = 256 * sizeof(int);
    size_t rsBytes   = (size_t)(n_nodes + 1) * sizeof(int);
    size_t need = hBytes + 2 * recBytes + bhBytes + partBytes + rsBytes;

    float* h   = (float*)ws;
    float* agg = (float*)d_out;

    // norm scratch aliases the rec region (rec is dead before norm runs)
    float* nrm_part = (float*)(ws + hBytes);
    float* nrm_musc = nrm_part + (size_t)n_graphs * NSPLIT * 128;

    mlp_kernel<<<(n_nodes + 63) / 64, 256, 0, stream>>>(x, states, Ws, W1, W2, h, n_nodes);

    const bool ok = (ws_size >= need) && (nb <= NB_MAX) && (n_nodes < (1 << 20));
    if (ok) {
        int2* rec      = (int2*)(ws + hBytes);
        int2* rec2     = (int2*)(ws + hBytes + recBytes);
        int*  bh       = (int*)(ws + hBytes + 2 * recBytes);
        int*  partials = (int*)(ws + hBytes + 2 * recBytes + bhBytes);
        int*  row_start= (int*)(ws + hBytes + 2 * recBytes + bhBytes + partBytes);

        binhist_kernel<<<nch, 256, 0, stream>>>(eidx, bh, n_edges, nb, nch);

        int nchunks = (nscan + SCAN_CHUNK - 1) / SCAN_CHUNK;
        scan1_kernel<<<nchunks, 256, 0, stream>>>(bh, bh, partials, nscan);  // in-place
        scan2_kernel<<<1, 256, 0, stream>>>(partials, nchunks);

        binscatter_kernel<<<nch, 256, 0, stream>>>(eidx, w, bh, partials, rec,
                                                   n_edges, nb, nch);

        bucket_sort_kernel<<<nb, 256, 0, stream>>>(bh, partials, rec, rec2, row_start,
                                                   n_edges, nb, nch, n_nodes);

        node_gather_kernel<<<(n_nodes + 3) / 4, 256, 0, stream>>>(row_start, rec2, h,
                                                                  agg, n_nodes);
    } else {
        hipMemsetAsync(agg, 0, hBytes, stream);
        long long sthreads = (long long)n_edges * 16;
        int sblocks = (int)((sthreads + 255) / 256);
        scatter_atomic_kernel<<<sblocks, 256, 0, stream>>>(eidx, w, h, agg, n_edges);
    }

    norm_part_kernel<<<n_graphs * NSPLIT, 256, 0, stream>>>(agg, nrm_part, npg);
    norm_fin_kernel<<<n_graphs, 64, 0, stream>>>(nrm_part, nrm_musc, gamma, npg);
    norm_apply_kernel<<<1024, 256, 0, stream>>>(agg, nrm_musc, beta, n_nodes, npg);
}